// Round 13
// baseline (2792.316 us; speedup 1.0000x reference)
//
#include <hip/hip_runtime.h>
#include <hip/hip_bf16.h>
#include <cstdint>

#define S_LEN 1024
#define DMODEL 1352
#define TD 4056
#define DFFN 2704
#define NHEAD 8
#define HDIM 169
#define NLAYER 7
#define LDAP 1376   // 1352 -> 43*32
#define KP2 2720    // 2704 -> 85*32
#define QS 1536     // 8 heads * 192
#define HP 192      // head dim padded to 6*32

typedef __attribute__((ext_vector_type(8))) short short8;
typedef __attribute__((ext_vector_type(4))) float f32x4;
typedef __attribute__((ext_vector_type(2))) unsigned short us2;
typedef __attribute__((ext_vector_type(4))) unsigned short us4;

__device__ __forceinline__ unsigned short f2bf(float f) {
    union { float f; unsigned int u; } c; c.f = f;
    unsigned int r = (c.u + 0x7fffu + ((c.u >> 16) & 1u)) >> 16;
    return (unsigned short)r;
}

__device__ __forceinline__ void g2l16(const void* g, void* l) {
    __builtin_amdgcn_global_load_lds((__attribute__((address_space(1))) void*)g,
                                     (__attribute__((address_space(3))) void*)l,
                                     16, 0, 0);
}

// ---------------- routing ----------------
__global__ __launch_bounds__(256) void route_k(const float* __restrict__ x,
                                               int* __restrict__ perm,
                                               int* __restrict__ pcnt) {
    const int tid = threadIdx.x;
    const int lane = tid & 63;
    const int w = tid >> 6;
    for (int i = tid; i < 4096; i += 256) perm[i] = -1;
    __syncthreads();
    int base = 0;
    for (int c = 0; c < 16; ++c) {
        const int t = c * 64 + lane;
        const float* xr = x + (long long)t * DMODEL;
        float best = xr[0]; int bi = 0;
        #pragma unroll
        for (int j = 1; j < 16; ++j) { float v = xr[j]; if (v > best) { best = v; bi = j; } }
        const bool match = ((bi & 3) == w);
        unsigned long long mb = __ballot(match);
        int pos = __popcll(mb & ((1ull << lane) - 1ull));
        if (match) perm[w * 1024 + base + pos] = t;
        base += __popcll(mb);
    }
    if (lane == 0) pcnt[w] = (base + 127) & ~127;
}

// ---------------- r11 tconv tile (proven): 32x32, [32][33] LDS ----------------
__device__ __forceinline__ void tconv_tile(const float* __restrict__ src,
    unsigned short* __restrict__ dst, int K, int N, int Kp, int kt, int nt,
    float (*t)[33])
{
    const int k0 = kt * 32, n0 = nt * 32;
    const int tx = threadIdx.x & 31, ty = threadIdx.x >> 5;
    #pragma unroll
    for (int i = 0; i < 4; ++i) {
        int k = k0 + ty + i * 8, n = n0 + tx;
        t[ty + i * 8][tx] = (k < K && n < N) ? src[(long long)k * N + n] : 0.f;
    }
    __syncthreads();
    #pragma unroll
    for (int i = 0; i < 2; ++i) {
        int s = threadIdx.x + i * 256;
        int nr = s >> 4;
        int kp = (s & 15) * 2;
        int n = n0 + nr;
        if (n < N) {
            us2 w; w.x = f2bf(t[kp][nr]); w.y = f2bf(t[kp + 1][nr]);
            *(us2*)&dst[(long long)n * Kp + k0 + kp] = w;
        }
    }
}

__device__ __forceinline__ void ln_row(const float* __restrict__ h,
    const float* __restrict__ g, const float* __restrict__ b,
    unsigned short* __restrict__ out, int row, float* sA, float* sB)
{
    const float* hr = h + (long long)row * DMODEL;
    float s = 0.f, s2 = 0.f;
    for (int j = threadIdx.x; j < DMODEL; j += 256) { float v = hr[j]; s += v; s2 += v * v; }
    #pragma unroll
    for (int o = 32; o; o >>= 1) { s += __shfl_xor(s, o, 64); s2 += __shfl_xor(s2, o, 64); }
    const int lane = threadIdx.x & 63, wid = threadIdx.x >> 6;
    if (lane == 0) { sA[wid] = s; sB[wid] = s2; }
    __syncthreads();
    s = sA[0] + sA[1] + sA[2] + sA[3];
    s2 = sB[0] + sB[1] + sB[2] + sB[3];
    const float mu = s / DMODEL;
    const float rstd = rsqrtf(fmaxf(s2 / DMODEL - mu * mu, 0.f) + 1e-5f);
    unsigned short* orow = out + (long long)row * LDAP;
    for (int j = threadIdx.x; j < LDAP; j += 256) {
        float v = (j < DMODEL) ? (hr[j] - mu) * rstd * g[j] + b[j] : 0.f;
        orow[j] = f2bf(v);
    }
}

// ---------------- prep1: tconv(wqkv) || tconv(wo) || LN1 (r11) ----------------
__global__ __launch_bounds__(256) void prep1_k(
    const float* __restrict__ wqkv_l, const float* __restrict__ wo_l,
    unsigned short* __restrict__ wqkvT, unsigned short* __restrict__ woT,
    const float* __restrict__ h, const float* __restrict__ g,
    const float* __restrict__ bb, unsigned short* __restrict__ lnA)
{
    __shared__ __align__(16) float t[32][33];
    __shared__ float sA[4], sB[4];
    const int b = blockIdx.x;
    if (b < 43 * 127) {
        tconv_tile(wqkv_l, wqkvT, DMODEL, TD, LDAP, b % 43, b / 43, t);
    } else if (b < 43 * 127 + 43 * 43) {
        const int c = b - 43 * 127;
        tconv_tile(wo_l, woT, DMODEL, DMODEL, LDAP, c % 43, c / 43, t);
    } else {
        ln_row(h, g, bb, lnA, b - (43 * 127 + 43 * 43), sA, sB);
    }
}

// ---------------- prep2: tconv(w1) || tconv(w2) || LN2 (r11) ------------------
__global__ __launch_bounds__(256) void prep2_k(
    const float* __restrict__ w1_l, const float* __restrict__ w2_l,
    unsigned short* __restrict__ w1T, unsigned short* __restrict__ w2T,
    const float* __restrict__ h, const float* __restrict__ g,
    const float* __restrict__ bb, unsigned short* __restrict__ lnA)
{
    __shared__ __align__(16) float t[32][33];
    __shared__ float sA[4], sB[4];
    const int b = blockIdx.x;
    if (b < 43 * 85 * 4) {
        const int kt = b % 43, rem = b / 43;
        const int nt = rem % 85, z = rem / 85;
        tconv_tile(w1_l + (long long)z * DMODEL * DFFN,
                   w1T + (long long)z * 2816 * LDAP,
                   DMODEL, DFFN, LDAP, kt, nt, t);
    } else if (b < 2 * 43 * 85 * 4) {
        const int c = b - 43 * 85 * 4;
        const int kt = c % 85, rem = c / 85;
        const int nt = rem % 43, z = rem / 43;
        tconv_tile(w2_l + (long long)z * DFFN * DMODEL,
                   w2T + (long long)z * 1408 * KP2,
                   DFFN, DMODEL, KP2, kt, nt, t);
    } else {
        ln_row(h, g, bb, lnA, b - 2 * 43 * 85 * 4, sA, sB);
    }
}

// ---------------- flash attention: 512 single-wave blocks, 16 q-rows each ------
// Port of r8's numerically-validated flash_phase. gw = blockIdx.x:
// head = gw>>6, qtile = gw&63, q0 = qtile*16. All inputs L3-hot.
__global__ __launch_bounds__(64) void flash_k(
    const unsigned short* __restrict__ qb,
    const unsigned short* __restrict__ kb,
    const unsigned short* __restrict__ VT,
    unsigned short* __restrict__ obuf,
    float scale) {
    const int gw = blockIdx.x;
    const int head = gw >> 6;
    const int q0 = (gw & 63) * 16;
    const int lane = threadIdx.x & 63;
    const int l15 = lane & 15, lg = lane >> 4;

    __shared__ unsigned short P_lds[16][40];
    __shared__ float stat[16];

    short8 qfr[6];
    #pragma unroll
    for (int c = 0; c < 6; ++c)
        qfr[c] = *(const short8*)&qb[(long long)(q0 + l15) * QS + head * HP + c * 32 + lg * 8];

    f32x4 acc[11] = {};
    float m_run = -1e30f, l_run = 0.f;
    const int nt = q0 / 32 + 1;
    for (int kt = 0; kt < nt; ++kt) {
        f32x4 st[2] = {};
        #pragma unroll
        for (int kf = 0; kf < 2; ++kf)
            #pragma unroll
            for (int c = 0; c < 6; ++c) {
                short8 a = *(const short8*)&kb[(long long)(kt * 32 + kf * 16 + l15) * QS + head * HP + c * 32 + lg * 8];
                st[kf] = __builtin_amdgcn_mfma_f32_16x16x32_bf16(a, qfr[c], st[kf], 0, 0, 0);
            }
        const bool diag = (kt == nt - 1);
        #pragma unroll
        for (int kf = 0; kf < 2; ++kf)
            #pragma unroll
            for (int r = 0; r < 4; ++r) {
                float s = st[kf][r] * scale;
                if (diag) {
                    const int kA = kt * 32 + kf * 16 + lg * 4 + r;
                    const int qA = q0 + l15;
                    if (kA > qA) s = -1e30f;
                }
                st[kf][r] = s;
            }
        float tmax = -1e30f;
        #pragma unroll
        for (int kf = 0; kf < 2; ++kf)
            #pragma unroll
            for (int r = 0; r < 4; ++r) tmax = fmaxf(tmax, st[kf][r]);
        tmax = fmaxf(tmax, __shfl_xor(tmax, 16, 64));
        tmax = fmaxf(tmax, __shfl_xor(tmax, 32, 64));
        const float mn = fmaxf(m_run, tmax);
        const float esc = __expf(m_run - mn);
        float tsum = 0.f;
        #pragma unroll
        for (int kf = 0; kf < 2; ++kf)
            #pragma unroll
            for (int r = 0; r < 4; ++r) {
                float p = __expf(st[kf][r] - mn);
                st[kf][r] = p; tsum += p;
            }
        tsum += __shfl_xor(tsum, 16, 64);
        tsum += __shfl_xor(tsum, 32, 64);
        l_run = l_run * esc + tsum;
        m_run = mn;
        if (lane < 16) stat[lane] = esc;
        #pragma unroll
        for (int kf = 0; kf < 2; ++kf) {
            us4 pk;
            #pragma unroll
            for (int r = 0; r < 4; ++r) pk[r] = f2bf(st[kf][r]);
            *(us4*)&P_lds[l15][kf * 16 + lg * 4] = pk;
        }
        f32x4 e = *(f32x4*)&stat[lg * 4];
        #pragma unroll
        for (int d = 0; d < 11; ++d)
            #pragma unroll
            for (int r = 0; r < 4; ++r) acc[d][r] *= e[r];
        short8 pa = *(const short8*)&P_lds[l15][lg * 8];
        #pragma unroll
        for (int d = 0; d < 11; ++d) {
            short8 vb = *(const short8*)&VT[(long long)(head * 256 + d * 16 + l15) * 1024 + kt * 32 + lg * 8];
            acc[d] = __builtin_amdgcn_mfma_f32_16x16x32_bf16(pa, vb, acc[d], 0, 0, 0);
        }
    }
    if (lane < 16) stat[lane] = l_run;
    f32x4 L = *(f32x4*)&stat[lg * 4];
    #pragma unroll
    for (int d = 0; d < 11; ++d) {
        const int dd = d * 16 + l15;
        if (dd >= HDIM) continue;
        #pragma unroll
        for (int r = 0; r < 4; ++r) {
            const int q = q0 + lg * 4 + r;
            obuf[(long long)q * LDAP + head * HDIM + dd] = f2bf(acc[d][r] / L[r]);
        }
    }
}

// ---------------- pipelined bf16 MFMA GEMM, 128x128x32, 8 waves (r11) ----------
template<int EPI, bool GATHER, int CAUSAL>
__global__ __launch_bounds__(512) void gemm2_k(
    const unsigned short* __restrict__ A_, int lda, long long zsA,
    const unsigned short* __restrict__ B_, int ldb, long long zsB,
    void* __restrict__ C_, int ldc, long long zsC,
    const float* __restrict__ bias_, long long zsBias,
    const int* __restrict__ perm_, const int* __restrict__ pcnt,
    int N, int Kp,
    unsigned short* __restrict__ q_, unsigned short* __restrict__ k_,
    unsigned short* __restrict__ vt_) {
    const int z = blockIdx.z;
    const int gm0 = blockIdx.y * 128;
    const int n0 = blockIdx.x * 128;
    if (pcnt && gm0 >= pcnt[z]) return;
    if (CAUSAL == 1 && n0 >= gm0 + 128) return;

    const unsigned short* A = A_ + (long long)z * zsA;
    const unsigned short* B = B_ + (long long)z * zsB;
    const float* bias = bias_ ? bias_ + (long long)z * zsBias : nullptr;
    const int* perm = perm_ ? perm_ + (long long)z * 1024 : nullptr;

    __shared__ unsigned short Al[3][128 * 32];
    __shared__ unsigned short Bl[3][128 * 32];

    const int tid = threadIdx.x, lane = tid & 63, wid = tid >> 6;   // wid 0..7
    const int wr = wid >> 2, wc = wid & 3;                          // 2M x 4N waves
    const int lrow = lane >> 2;        // 0..15

    // staging: lane (4r+c) fetches global k-segment (c ^ ((r>>1)&3)) of row r
    const int lseg = (((lane & 3) ^ ((lane >> 3) & 3)) * 8);

    const int srow = wid * 16 + lrow;
    int ar = gm0 + srow;
    if (GATHER) { const int p = perm[ar]; ar = (p < 0) ? 0 : p; }
    const unsigned short* gA = A + (long long)ar * lda + lseg;
    const unsigned short* gB = B + (long long)(n0 + srow) * ldb + lseg;
    const int ldsOff = wid * 512;      // wave-uniform LDS base (elements)

    int nt = Kp >> 5;
    if (CAUSAL == 2) { int ke = gm0 + 128; if (ke > Kp) ke = Kp; nt = ke >> 5; }

    f32x4 acc[4][2] = {};

    // prologue: issue tiles 0 and 1 (2 vmem ops per wave per tile)
    {
        const int t1 = (nt > 1) ? 1 : 0;
        g2l16(gA, &Al[0][ldsOff]);
        g2l16(gB, &Bl[0][ldsOff]);
        g2l16(gA + t1 * 32, &Al[1][ldsOff]);
        g2l16(gB + t1 * 32, &Bl[1][ldsOff]);
    }

    const int l15 = lane & 15;
    // fragment read: logical k-segment (lane>>4), physical = ^((l15>>1)&3)
    const int ksw = (((lane >> 4) ^ ((l15 >> 1) & 3)) * 8);

    for (int t = 0; t < nt; ++t) {
        asm volatile("s_waitcnt vmcnt(2)" ::: "memory");
        __builtin_amdgcn_s_barrier();
        __builtin_amdgcn_sched_barrier(0);
        {
            const int ts = (t + 2 < nt) ? t + 2 : nt - 1;
            const int ko = ts * 32;
            const int bi = (t + 2) % 3;
            g2l16(gA + ko, &Al[bi][ldsOff]);
            g2l16(gB + ko, &Bl[bi][ldsOff]);
        }
        const int cur = t % 3;
        short8 af[4], bfv[2];
        #pragma unroll
        for (int m = 0; m < 4; ++m)
            af[m] = *(const short8*)&Al[cur][(wr * 64 + m * 16 + l15) * 32 + ksw];
        #pragma unroll
        for (int n = 0; n < 2; ++n)
            bfv[n] = *(const short8*)&Bl[cur][(wc * 32 + n * 16 + l15) * 32 + ksw];
        #pragma unroll
        for (int m = 0; m < 4; ++m)
            #pragma unroll
            for (int n = 0; n < 2; ++n)
                acc[m][n] = __builtin_amdgcn_mfma_f32_16x16x32_bf16(af[m], bfv[n], acc[m][n], 0, 0, 0);
    }

    // DRAIN: no LDS-DMA may be in flight at s_endpgm (round-3 race)
    asm volatile("s_waitcnt vmcnt(0) lgkmcnt(0)" ::: "memory");

    const int lq = (lane >> 4) * 4;
    #pragma unroll
    for (int m = 0; m < 4; ++m) {
        const int trow = wr * 64 + m * 16 + lq;
        #pragma unroll
        for (int n = 0; n < 2; ++n) {
            const int col = n0 + wc * 32 + n * 16 + l15;
            if (col >= N) continue;
            const float bv = bias ? bias[col] : 0.f;
            if (EPI == 5) {
                const int role = col / 1352;
                const int within = col - role * 1352;
                const int hh = within / 169;
                const int dd = within - hh * 169;
                if (role == 2) {
                    us4 pk;
                    #pragma unroll
                    for (int r = 0; r < 4; ++r) pk[r] = f2bf(acc[m][n][r] + bv);
                    *(us4*)&vt_[(long long)(hh * 256 + dd) * 1024 + gm0 + trow] = pk;
                } else {
                    unsigned short* dstb = role ? k_ : q_;
                    #pragma unroll
                    for (int r = 0; r < 4; ++r)
                        dstb[(long long)(gm0 + trow + r) * QS + hh * HP + dd] =
                            f2bf(acc[m][n][r] + bv);
                }
            } else {
                #pragma unroll
                for (int r = 0; r < 4; ++r) {
                    const int grow = gm0 + trow + r;
                    const float v = acc[m][n][r] + bv;
                    if (EPI == 0) {
                        ((float*)C_)[(long long)z * zsC + (long long)grow * ldc + col] = v;
                    } else if (EPI == 1) {
                        const int tok = perm[grow];
                        ((unsigned short*)C_)[(long long)z * zsC + (long long)grow * ldc + col] =
                            (tok >= 0) ? f2bf(fmaxf(v, 0.f)) : (unsigned short)0;
                    } else if (EPI == 2) {
                        ((float*)C_)[(long long)grow * ldc + col] += v;
                    } else if (EPI == 3) {
                        const int tok = perm[grow];
                        if (tok >= 0) ((float*)C_)[(long long)tok * ldc + col] += v;
                    }
                }
            }
        }
    }
}

extern "C" void kernel_launch(void* const* d_in, const int* in_sizes, int n_in,
                              void* d_out, int out_size, void* d_ws, size_t ws_size,
                              hipStream_t stream) {
    const float* x     = (const float*)d_in[0];
    const float* ln1_g = (const float*)d_in[1];
    const float* ln1_b = (const float*)d_in[2];
    const float* wqkv  = (const float*)d_in[3];
    const float* bqkv  = (const float*)d_in[4];
    const float* wo    = (const float*)d_in[5];
    const float* bo    = (const float*)d_in[6];
    const float* ln2_g = (const float*)d_in[7];
    const float* ln2_b = (const float*)d_in[8];
    const float* w1    = (const float*)d_in[9];
    const float* b1    = (const float*)d_in[10];
    const float* w2    = (const float*)d_in[11];
    const float* b2    = (const float*)d_in[12];

    float* h = (float*)d_out;

    char* w = (char*)d_ws;
    auto alloc = [&](size_t bytes) { void* p = w; w += (bytes + 255) & ~255ull; return p; };
    unsigned short* lnA   = (unsigned short*)alloc((size_t)S_LEN * LDAP * 2);
    unsigned short* qb    = (unsigned short*)alloc((size_t)S_LEN * QS * 2);
    unsigned short* kb    = (unsigned short*)alloc((size_t)S_LEN * QS * 2);
    unsigned short* VT    = (unsigned short*)alloc((size_t)NHEAD * 256 * 1024 * 2);
    unsigned short* obufb = (unsigned short*)alloc((size_t)S_LEN * LDAP * 2);
    unsigned short* hid   = (unsigned short*)alloc((size_t)4096 * KP2 * 2);
    unsigned short* wqkvT = (unsigned short*)alloc((size_t)4096 * LDAP * 2);
    unsigned short* woT   = (unsigned short*)alloc((size_t)1408 * LDAP * 2);
    char*           U     = (char*)alloc((size_t)62000000);
    int* perm = (int*)alloc(4096 * 4);
    int* pcnt = (int*)alloc(64);

    unsigned short* w1T = (unsigned short*)U;
    unsigned short* w2T = (unsigned short*)(U + (size_t)4 * 2816 * LDAP * 2);

    hipMemcpyAsync(h, x, (size_t)S_LEN * DMODEL * 4, hipMemcpyDeviceToDevice, stream);
    // q/k head-pad slots enter the QK^T MFMA -> must be zero; V pad rows read by PV
    hipMemsetAsync(qb, 0, (size_t)S_LEN * QS * 2, stream);
    hipMemsetAsync(kb, 0, (size_t)S_LEN * QS * 2, stream);
    hipMemsetAsync(VT, 0, (size_t)NHEAD * 256 * 1024 * 2, stream);
    route_k<<<1, 256, 0, stream>>>(x, perm, pcnt);

    const float scale = 1.0f / 13.0f;

    for (int l = 0; l < NLAYER; ++l) {
        const float* wqkv_l = wqkv + (long long)l * DMODEL * TD;
        const float* wo_l   = wo   + (long long)l * DMODEL * DMODEL;
        const float* w1_l   = w1   + (long long)l * 4 * DMODEL * DFFN;
        const float* w2_l   = w2   + (long long)l * 4 * DFFN * DMODEL;

        // fused: tconv(wqkv) || tconv(wo) || LN1
        prep1_k<<<43 * 127 + 43 * 43 + 1024, 256, 0, stream>>>(
            wqkv_l, wo_l, wqkvT, woT, h, ln1_g + l * DMODEL, ln1_b + l * DMODEL, lnA);
        // QKV -> split bf16 q/k (head-padded) + V transposed
        gemm2_k<5, false, 0><<<dim3(32, 8, 1), 512, 0, stream>>>(
            lnA, LDAP, 0, wqkvT, LDAP, 0, nullptr, 0, 0,
            bqkv + l * TD, 0, nullptr, nullptr, TD, LDAP, qb, kb, VT);
        // fused flash attention (512 single-wave blocks) -> obufb
        flash_k<<<512, 64, 0, stream>>>(qb, kb, VT, obufb, scale);
        // h += o @ wo + bo
        gemm2_k<2, false, 0><<<dim3(11, 8, 1), 512, 0, stream>>>(
            obufb, LDAP, 0, woT, LDAP, 0, h, DMODEL, 0,
            bo + l * DMODEL, 0, nullptr, nullptr, DMODEL, LDAP, nullptr, nullptr, nullptr);

        // fused: tconv(w1) || tconv(w2) || LN2
        prep2_k<<<2 * 43 * 85 * 4 + 1024, 256, 0, stream>>>(
            w1_l, w2_l, w1T, w2T, h, ln2_g + l * DMODEL, ln2_b + l * DMODEL, lnA);
        // hid = relu(gather(lnA) @ w1[e] + b1[e]) -> bf16
        gemm2_k<1, true, 0><<<dim3(22, 8, 4), 512, 0, stream>>>(
            lnA, LDAP, 0, w1T, LDAP, (long long)2816 * LDAP,
            hid, KP2, (long long)1024 * KP2,
            b1 + (long long)l * 4 * DFFN, DFFN, perm, pcnt, DFFN, LDAP,
            nullptr, nullptr, nullptr);
        // h[tok] += hid @ w2[e] + b2[e]
        gemm2_k<3, false, 0><<<dim3(11, 8, 4), 512, 0, stream>>>(
            hid, KP2, (long long)1024 * KP2, w2T, KP2, (long long)1408 * KP2,
            h, DMODEL, 0,
            b2 + (long long)l * 4 * DMODEL, DMODEL, perm, pcnt, DMODEL, KP2,
            nullptr, nullptr, nullptr);
    }
}

// Round 14
// 2120.291 us; speedup vs baseline: 1.3169x; 1.3169x over previous
//
#include <hip/hip_runtime.h>
#include <hip/hip_bf16.h>
#include <cstdint>

#define S_LEN 1024
#define DMODEL 1352
#define TD 4056
#define DFFN 2704
#define NHEAD 8
#define HDIM 169
#define NLAYER 7
#define LDAP 1408   // 1352 -> 44*32 = 22*64
#define KP2 2752    // 2704 -> 86*32 = 43*64
#define QS 1536     // 8 heads * 192
#define HP 192      // head dim padded to 3*64

typedef __attribute__((ext_vector_type(8))) short short8;
typedef __attribute__((ext_vector_type(4))) float f32x4;
typedef __attribute__((ext_vector_type(2))) unsigned short us2;
typedef __attribute__((ext_vector_type(4))) unsigned short us4;

__device__ __forceinline__ unsigned short f2bf(float f) {
    union { float f; unsigned int u; } c; c.f = f;
    unsigned int r = (c.u + 0x7fffu + ((c.u >> 16) & 1u)) >> 16;
    return (unsigned short)r;
}

__device__ __forceinline__ void g2l16(const void* g, void* l) {
    __builtin_amdgcn_global_load_lds((__attribute__((address_space(1))) void*)g,
                                     (__attribute__((address_space(3))) void*)l,
                                     16, 0, 0);
}

// ---------------- routing ----------------
__global__ __launch_bounds__(256) void route_k(const float* __restrict__ x,
                                               int* __restrict__ perm,
                                               int* __restrict__ pcnt) {
    const int tid = threadIdx.x;
    const int lane = tid & 63;
    const int w = tid >> 6;
    for (int i = tid; i < 4096; i += 256) perm[i] = -1;
    __syncthreads();
    int base = 0;
    for (int c = 0; c < 16; ++c) {
        const int t = c * 64 + lane;
        const float* xr = x + (long long)t * DMODEL;
        float best = xr[0]; int bi = 0;
        #pragma unroll
        for (int j = 1; j < 16; ++j) { float v = xr[j]; if (v > best) { best = v; bi = j; } }
        const bool match = ((bi & 3) == w);
        unsigned long long mb = __ballot(match);
        int pos = __popcll(mb & ((1ull << lane) - 1ull));
        if (match) perm[w * 1024 + base + pos] = t;
        base += __popcll(mb);
    }
    if (lane == 0) pcnt[w] = (base + 127) & ~127;
}

// ---------------- r11 tconv tile (proven): 32x32, [32][33] LDS ----------------
__device__ __forceinline__ void tconv_tile(const float* __restrict__ src,
    unsigned short* __restrict__ dst, int K, int N, int Kp, int kt, int nt,
    float (*t)[33])
{
    const int k0 = kt * 32, n0 = nt * 32;
    const int tx = threadIdx.x & 31, ty = threadIdx.x >> 5;
    #pragma unroll
    for (int i = 0; i < 4; ++i) {
        int k = k0 + ty + i * 8, n = n0 + tx;
        t[ty + i * 8][tx] = (k < K && n < N) ? src[(long long)k * N + n] : 0.f;
    }
    __syncthreads();
    #pragma unroll
    for (int i = 0; i < 2; ++i) {
        int s = threadIdx.x + i * 256;
        int nr = s >> 4;
        int kp = (s & 15) * 2;
        int n = n0 + nr;
        if (n < N) {
            us2 w; w.x = f2bf(t[kp][nr]); w.y = f2bf(t[kp + 1][nr]);
            *(us2*)&dst[(long long)n * Kp + k0 + kp] = w;
        }
    }
}

__device__ __forceinline__ void ln_row(const float* __restrict__ h,
    const float* __restrict__ g, const float* __restrict__ b,
    unsigned short* __restrict__ out, int row, float* sA, float* sB)
{
    const float* hr = h + (long long)row * DMODEL;
    float s = 0.f, s2 = 0.f;
    for (int j = threadIdx.x; j < DMODEL; j += 256) { float v = hr[j]; s += v; s2 += v * v; }
    #pragma unroll
    for (int o = 32; o; o >>= 1) { s += __shfl_xor(s, o, 64); s2 += __shfl_xor(s2, o, 64); }
    const int lane = threadIdx.x & 63, wid = threadIdx.x >> 6;
    if (lane == 0) { sA[wid] = s; sB[wid] = s2; }
    __syncthreads();
    s = sA[0] + sA[1] + sA[2] + sA[3];
    s2 = sB[0] + sB[1] + sB[2] + sB[3];
    const float mu = s / DMODEL;
    const float rstd = rsqrtf(fmaxf(s2 / DMODEL - mu * mu, 0.f) + 1e-5f);
    unsigned short* orow = out + (long long)row * LDAP;
    for (int j = threadIdx.x; j < LDAP; j += 256) {
        float v = (j < DMODEL) ? (hr[j] - mu) * rstd * g[j] + b[j] : 0.f;
        orow[j] = f2bf(v);
    }
}

// ---------------- prep1: tconv(wqkv) || tconv(wo) || LN1 ----------------
__global__ __launch_bounds__(256) void prep1_k(
    const float* __restrict__ wqkv_l, const float* __restrict__ wo_l,
    unsigned short* __restrict__ wqkvT, unsigned short* __restrict__ woT,
    const float* __restrict__ h, const float* __restrict__ g,
    const float* __restrict__ bb, unsigned short* __restrict__ lnA)
{
    __shared__ __align__(16) float t[32][33];
    __shared__ float sA[4], sB[4];
    const int b = blockIdx.x;
    if (b < 44 * 127) {
        tconv_tile(wqkv_l, wqkvT, DMODEL, TD, LDAP, b % 44, b / 44, t);
    } else if (b < 44 * 127 + 44 * 43) {
        const int c = b - 44 * 127;
        tconv_tile(wo_l, woT, DMODEL, DMODEL, LDAP, c % 44, c / 44, t);
    } else {
        ln_row(h, g, bb, lnA, b - (44 * 127 + 44 * 43), sA, sB);
    }
}

// ---------------- prep2: tconv(w1) || tconv(w2) || LN2 ------------------
__global__ __launch_bounds__(256) void prep2_k(
    const float* __restrict__ w1_l, const float* __restrict__ w2_l,
    unsigned short* __restrict__ w1T, unsigned short* __restrict__ w2T,
    const float* __restrict__ h, const float* __restrict__ g,
    const float* __restrict__ bb, unsigned short* __restrict__ lnA)
{
    __shared__ __align__(16) float t[32][33];
    __shared__ float sA[4], sB[4];
    const int b = blockIdx.x;
    if (b < 44 * 85 * 4) {
        const int kt = b % 44, rem = b / 44;
        const int nt = rem % 85, z = rem / 85;
        tconv_tile(w1_l + (long long)z * DMODEL * DFFN,
                   w1T + (long long)z * 2816 * LDAP,
                   DMODEL, DFFN, LDAP, kt, nt, t);
    } else if (b < 44 * 85 * 4 + 86 * 43 * 4) {
        const int c = b - 44 * 85 * 4;
        const int kt = c % 86, rem = c / 86;
        const int nt = rem % 43, z = rem / 43;
        tconv_tile(w2_l + (long long)z * DFFN * DMODEL,
                   w2T + (long long)z * 1408 * KP2,
                   DFFN, DMODEL, KP2, kt, nt, t);
    } else {
        ln_row(h, g, bb, lnA, b - (44 * 85 * 4 + 86 * 43 * 4), sA, sB);
    }
}

// ---------------- causal row softmax (scores f32 -> P bf16) ----------------
__global__ __launch_bounds__(256) void softmax_k(const float* __restrict__ scores,
                                                 unsigned short* __restrict__ P,
                                                 float scale) {
    const int i = blockIdx.x;
    const long long rb = ((long long)blockIdx.y * 1024 + i) * 1024;
    const float* srow = scores + rb;
    unsigned short* prow = P + rb;
    const int n = i + 1;
    float mx = -3.4e38f;
    for (int j = threadIdx.x; j < n; j += 256) mx = fmaxf(mx, srow[j]);
    __shared__ float sA[4], sB[4];
    #pragma unroll
    for (int o = 32; o; o >>= 1) mx = fmaxf(mx, __shfl_xor(mx, o, 64));
    const int lane = threadIdx.x & 63, wid = threadIdx.x >> 6;
    if (lane == 0) sA[wid] = mx;
    __syncthreads();
    mx = fmaxf(fmaxf(sA[0], sA[1]), fmaxf(sA[2], sA[3])) * scale;
    float sum = 0.f;
    for (int j = threadIdx.x; j < n; j += 256) sum += __expf(srow[j] * scale - mx);
    #pragma unroll
    for (int o = 32; o; o >>= 1) sum += __shfl_xor(sum, o, 64);
    if (lane == 0) sB[wid] = sum;
    __syncthreads();
    const float inv = 1.f / (sB[0] + sB[1] + sB[2] + sB[3]);
    const int nz = ((i >> 7) + 1) << 7;
    for (int j = threadIdx.x; j < nz; j += 256) {
        float p = (j < n) ? __expf(srow[j] * scale - mx) * inv : 0.f;
        prow[j] = f2bf(p);
    }
}

// ---------------- pipelined bf16 MFMA GEMM, 128x128x64, 8 waves ----------------
// BK=64: 4 LDS buffers (128KB), 3-deep prefetch, vmcnt(8), ONE barrier per
// 16 MFMA/wave (vs one per 8 at BK=32). Bank-conflict fix (rule #21,
// both-sides involution with linear gload_lds dest): 16B slot s of row r
// lives at physical slot s ^ (r&7); staging pre-swizzles the GLOBAL source
// column, ds_read applies the same XOR -> 2-way (free) instead of 16-way.
template<int EPI, bool GATHER, int CAUSAL>
__global__ __launch_bounds__(512) void gemm2_k(
    const unsigned short* __restrict__ A_, int lda, long long zsA,
    const unsigned short* __restrict__ B_, int ldb, long long zsB,
    void* __restrict__ C_, int ldc, long long zsC,
    const float* __restrict__ bias_, long long zsBias,
    const int* __restrict__ perm_, const int* __restrict__ pcnt,
    int N, int Kp,
    unsigned short* __restrict__ q_, unsigned short* __restrict__ k_,
    unsigned short* __restrict__ vt_) {
    const int z = blockIdx.z;
    const int gm0 = blockIdx.y * 128;
    const int n0 = blockIdx.x * 128;
    if (pcnt && gm0 >= pcnt[z]) return;
    if (CAUSAL == 1 && n0 >= gm0 + 128) return;

    const unsigned short* A = A_ + (long long)z * zsA;
    const unsigned short* B = B_ + (long long)z * zsB;
    const float* bias = bias_ ? bias_ + (long long)z * zsBias : nullptr;
    const int* perm = perm_ ? perm_ + (long long)z * 1024 : nullptr;

    __shared__ unsigned short Al[4][128 * 64];   // 64 KB
    __shared__ unsigned short Bl[4][128 * 64];   // 64 KB

    const int tid = threadIdx.x, lane = tid & 63, wid = tid >> 6;   // wid 0..7
    const int wr = wid >> 2, wc = wid & 3;                          // 2M x 4N waves
    const int l15 = lane & 15, lg = lane >> 4;

    // staging: load j covers rows wid*16+j*8 .. +7; lane l -> row sub (l>>3),
    // physical slot (l&7); fetch global slot (l&7)^(l>>3)  [row&7 == l>>3]
    const int sr = lane >> 3;             // 0..7
    const int scs = (lane & 7) ^ sr;      // pre-swizzled global 16B-slot

    const unsigned short* gA[2];
    const unsigned short* gB[2];
    #pragma unroll
    for (int j = 0; j < 2; ++j) {
        const int row = wid * 16 + j * 8 + sr;
        int ar = gm0 + row;
        if (GATHER) { const int p = perm[ar]; ar = (p < 0) ? 0 : p; }
        gA[j] = A + (long long)ar * lda + scs * 8;
        gB[j] = B + (long long)(n0 + row) * ldb + scs * 8;
    }
    const int ldsW = wid * 1024;          // wave base (elements) within buffer

    int nt = Kp >> 6;
    if (CAUSAL == 2) { int ke = gm0 + 128; if (ke > Kp) ke = Kp; nt = ke >> 6; }

    f32x4 acc[4][2] = {};

    // prologue: issue tiles 0,1,2 (4 vmem ops per wave per tile; clamped)
    #pragma unroll
    for (int tt = 0; tt < 3; ++tt) {
        const int ts = (tt < nt) ? tt : nt - 1;
        const int ko = ts * 64;
        #pragma unroll
        for (int j = 0; j < 2; ++j) {
            g2l16(gA[j] + ko, &Al[tt][ldsW + j * 512]);
            g2l16(gB[j] + ko, &Bl[tt][ldsW + j * 512]);
        }
    }

    for (int t = 0; t < nt; ++t) {
        // 8 newest loads = tiles t+1,t+2 -> tile t resident after this wait
        asm volatile("s_waitcnt vmcnt(8)" ::: "memory");
        __builtin_amdgcn_s_barrier();
        __builtin_amdgcn_sched_barrier(0);
        // issue tile t+3 into buffer (t+3)&3 (distinct from cur=t&3)
        {
            const int ts = (t + 3 < nt) ? t + 3 : nt - 1;
            const int ko = ts * 64;
            const int bi = (t + 3) & 3;
            #pragma unroll
            for (int j = 0; j < 2; ++j) {
                g2l16(gA[j] + ko, &Al[bi][ldsW + j * 512]);
                g2l16(gB[j] + ko, &Bl[bi][ldsW + j * 512]);
            }
        }
        const int cur = t & 3;
        short8 af[4][2], bfv[2][2];
        #pragma unroll
        for (int m = 0; m < 4; ++m)
            #pragma unroll
            for (int s = 0; s < 2; ++s)
                af[m][s] = *(const short8*)&Al[cur][(wr * 64 + m * 16 + l15) * 64 +
                                                    (((s * 4 + lg) ^ (l15 & 7)) * 8)];
        #pragma unroll
        for (int n = 0; n < 2; ++n)
            #pragma unroll
            for (int s = 0; s < 2; ++s)
                bfv[n][s] = *(const short8*)&Bl[cur][(wc * 32 + n * 16 + l15) * 64 +
                                                     (((s * 4 + lg) ^ (l15 & 7)) * 8)];
        #pragma unroll
        for (int s = 0; s < 2; ++s)
            #pragma unroll
            for (int m = 0; m < 4; ++m)
                #pragma unroll
                for (int n = 0; n < 2; ++n)
                    acc[m][n] = __builtin_amdgcn_mfma_f32_16x16x32_bf16(af[m][s], bfv[n][s], acc[m][n], 0, 0, 0);
    }

    // DRAIN: no LDS-DMA may be in flight at s_endpgm (round-3 race)
    asm volatile("s_waitcnt vmcnt(0) lgkmcnt(0)" ::: "memory");

    const int lq = lg * 4;
    #pragma unroll
    for (int m = 0; m < 4; ++m) {
        const int trow = wr * 64 + m * 16 + lq;
        #pragma unroll
        for (int n = 0; n < 2; ++n) {
            const int col = n0 + wc * 32 + n * 16 + l15;
            if (col >= N) continue;
            const float bv = bias ? bias[col] : 0.f;
            if (EPI == 5) {
                const int role = col / 1352;
                const int within = col - role * 1352;
                const int hh = within / 169;
                const int dd = within - hh * 169;
                if (role == 2) {
                    us4 pk;
                    #pragma unroll
                    for (int r = 0; r < 4; ++r) pk[r] = f2bf(acc[m][n][r] + bv);
                    *(us4*)&vt_[(long long)(hh * 256 + dd) * 1024 + gm0 + trow] = pk;
                } else {
                    unsigned short* dstb = role ? k_ : q_;
                    #pragma unroll
                    for (int r = 0; r < 4; ++r)
                        dstb[(long long)(gm0 + trow + r) * QS + hh * HP + dd] =
                            f2bf(acc[m][n][r] + bv);
                }
            } else {
                #pragma unroll
                for (int r = 0; r < 4; ++r) {
                    const int grow = gm0 + trow + r;
                    const float v = acc[m][n][r] + bv;
                    if (EPI == 0) {
                        ((float*)C_)[(long long)z * zsC + (long long)grow * ldc + col] = v;
                    } else if (EPI == 1) {
                        const int tok = perm[grow];
                        ((unsigned short*)C_)[(long long)z * zsC + (long long)grow * ldc + col] =
                            (tok >= 0) ? f2bf(fmaxf(v, 0.f)) : (unsigned short)0;
                    } else if (EPI == 2) {
                        ((float*)C_)[(long long)grow * ldc + col] += v;
                    } else if (EPI == 3) {
                        const int tok = perm[grow];
                        if (tok >= 0) ((float*)C_)[(long long)tok * ldc + col] += v;
                    } else if (EPI == 6) {
                        ((unsigned short*)C_)[(long long)grow * ldc + z * 169 + col] = f2bf(v);
                    }
                }
            }
        }
    }
}

extern "C" void kernel_launch(void* const* d_in, const int* in_sizes, int n_in,
                              void* d_out, int out_size, void* d_ws, size_t ws_size,
                              hipStream_t stream) {
    const float* x     = (const float*)d_in[0];
    const float* ln1_g = (const float*)d_in[1];
    const float* ln1_b = (const float*)d_in[2];
    const float* wqkv  = (const float*)d_in[3];
    const float* bqkv  = (const float*)d_in[4];
    const float* wo    = (const float*)d_in[5];
    const float* bo    = (const float*)d_in[6];
    const float* ln2_g = (const float*)d_in[7];
    const float* ln2_b = (const float*)d_in[8];
    const float* w1    = (const float*)d_in[9];
    const float* b1    = (const float*)d_in[10];
    const float* w2    = (const float*)d_in[11];
    const float* b2    = (const float*)d_in[12];

    float* h = (float*)d_out;

    char* w = (char*)d_ws;
    auto alloc = [&](size_t bytes) { void* p = w; w += (bytes + 255) & ~255ull; return p; };
    unsigned short* lnA   = (unsigned short*)alloc((size_t)S_LEN * LDAP * 2);
    unsigned short* qb    = (unsigned short*)alloc((size_t)S_LEN * QS * 2);
    unsigned short* kb    = (unsigned short*)alloc((size_t)S_LEN * QS * 2);
    unsigned short* VT    = (unsigned short*)alloc((size_t)NHEAD * 256 * 1024 * 2);
    unsigned short* obufb = (unsigned short*)alloc((size_t)S_LEN * LDAP * 2);
    unsigned short* hid   = (unsigned short*)alloc((size_t)4096 * KP2 * 2);
    unsigned short* wqkvT = (unsigned short*)alloc((size_t)4096 * LDAP * 2);
    unsigned short* woT   = (unsigned short*)alloc((size_t)1408 * LDAP * 2);
    char*           U     = (char*)alloc((size_t)64000000);   // union (time-aliased, L3-hot)
    int* perm = (int*)alloc(4096 * 4);
    int* pcnt = (int*)alloc(64);

    float*          scores = (float*)U;
    unsigned short* Pbuf   = (unsigned short*)(U + (size_t)NHEAD * 1024 * 1024 * 4);
    unsigned short* w1T    = (unsigned short*)U;
    unsigned short* w2T    = (unsigned short*)(U + (size_t)4 * 2816 * LDAP * 2);

    hipMemcpyAsync(h, x, (size_t)S_LEN * DMODEL * 4, hipMemcpyDeviceToDevice, stream);
    // q/k head-pad slots enter the scores MFMA -> must be zero
    hipMemsetAsync(qb, 0, (size_t)S_LEN * QS * 2, stream);
    hipMemsetAsync(kb, 0, (size_t)S_LEN * QS * 2, stream);
    route_k<<<1, 256, 0, stream>>>(x, perm, pcnt);

    const float scale = 1.0f / 13.0f;

    for (int l = 0; l < NLAYER; ++l) {
        const float* wqkv_l = wqkv + (long long)l * DMODEL * TD;
        const float* wo_l   = wo   + (long long)l * DMODEL * DMODEL;
        const float* w1_l   = w1   + (long long)l * 4 * DMODEL * DFFN;
        const float* w2_l   = w2   + (long long)l * 4 * DFFN * DMODEL;

        // fused: tconv(wqkv) || tconv(wo) || LN1
        prep1_k<<<44 * 127 + 44 * 43 + 1024, 256, 0, stream>>>(
            wqkv_l, wo_l, wqkvT, woT, h, ln1_g + l * DMODEL, ln1_b + l * DMODEL, lnA);
        // QKV -> split bf16 q/k (head-padded) + V transposed
        gemm2_k<5, false, 0><<<dim3(32, 8, 1), 512, 0, stream>>>(
            lnA, LDAP, 0, wqkvT, LDAP, 0, nullptr, 0, 0,
            bqkv + l * TD, 0, nullptr, nullptr, TD, LDAP, qb, kb, VT);
        // scores = q @ k^T per head (causal tiles only)
        gemm2_k<0, false, 1><<<dim3(8, 8, 8), 512, 0, stream>>>(
            qb, QS, HP, kb, QS, HP, scores, 1024, 1024 * 1024,
            nullptr, 0, nullptr, nullptr, 1024, HP, nullptr, nullptr, nullptr);
        softmax_k<<<dim3(1024, NHEAD), 256, 0, stream>>>(scores, Pbuf, scale);
        // o = P @ v per head -> compact bf16 [1024][1408]
        gemm2_k<6, false, 2><<<dim3(2, 8, 8), 512, 0, stream>>>(
            Pbuf, 1024, 1024 * 1024, VT, 1024, 256 * 1024, obufb, LDAP, 0,
            nullptr, 0, nullptr, nullptr, HDIM, 1024, nullptr, nullptr, nullptr);
        // h += o @ wo + bo
        gemm2_k<2, false, 0><<<dim3(11, 8, 1), 512, 0, stream>>>(
            obufb, LDAP, 0, woT, LDAP, 0, h, DMODEL, 0,
            bo + l * DMODEL, 0, nullptr, nullptr, DMODEL, LDAP, nullptr, nullptr, nullptr);

        // fused: tconv(w1) || tconv(w2) || LN2  (overwrites scores/Pbuf union; both dead)
        prep2_k<<<44 * 85 * 4 + 86 * 43 * 4 + 1024, 256, 0, stream>>>(
            w1_l, w2_l, w1T, w2T, h, ln2_g + l * DMODEL, ln2_b + l * DMODEL, lnA);
        // hid = relu(gather(lnA) @ w1[e] + b1[e]) -> bf16
        gemm2_k<1, true, 0><<<dim3(22, 8, 4), 512, 0, stream>>>(
            lnA, LDAP, 0, w1T, LDAP, (long long)2816 * LDAP,
            hid, KP2, (long long)1024 * KP2,
            b1 + (long long)l * 4 * DFFN, DFFN, perm, pcnt, DFFN, LDAP,
            nullptr, nullptr, nullptr);
        // h[tok] += hid @ w2[e] + b2[e]
        gemm2_k<3, false, 0><<<dim3(11, 8, 4), 512, 0, stream>>>(
            hid, KP2, (long long)1024 * KP2, w2T, KP2, (long long)1408 * KP2,
            h, DMODEL, 0,
            b2 + (long long)l * 4 * DMODEL, DMODEL, perm, pcnt, DMODEL, KP2,
            nullptr, nullptr, nullptr);
    }
}